// Round 1
// baseline (1698.528 us; speedup 1.0000x reference)
//
#include <hip/hip_runtime.h>
#include <math.h>

#pragma clang fp contract(off)

#define HW      (2048*2048)
#define NI      4096        // instances per image
#define MAXPIX  1024        // pixels per instance (equal partition)
#define NF      200
#define FEAT    209
#define NE      (NI*2)      // edges = N1 * TOPN
#define XSIZE   ((2*NI)*FEAT)      // 1712128 floats
#define EIOFF   XSIZE
#define EASIZE  (NE*6)
#define EAOFF   (EIOFF + 2*NE)

// ---------------- init: zero x region + zflow accumulators ----------------
__global__ void zero_kernel(float* out, float* zf) {
    long i = (long)blockIdx.x * blockDim.x + threadIdx.x;
    for (long p = i; p < (long)XSIZE; p += (long)gridDim.x * blockDim.x) out[p] = 0.f;
    if (i < 2*NI) zf[i] = 0.f;
}

// ---------------- interp contribution table: rank -> (k, weight) ----------
__global__ void table_kernel(int* tk0, float* tw0, int* tk1, float* tw1) {
    int t = threadIdx.x;
    for (int r = t; r < MAXPIX; r += blockDim.x) { tk0[r] = -1; tk1[r] = -1; tw0[r] = 0.f; tw1[r] = 0.f; }
    __syncthreads();
    if (t < NF) {
        float scale = (float)MAXPIX / (float)NF;           // 1024/200 in f32, same as ref
        float p = ((float)t + 0.5f) * scale - 0.5f;
        p = fminf(fmaxf(p, 0.0f), (float)(MAXPIX - 1));
        int i0 = (int)floorf(p);
        int i1 = min(i0 + 1, MAXPIX - 1);
        float w = p - (float)i0;
        tk0[i0] = t; tw0[i0] = 1.0f - w;                   // v[i0]*(1-w)
        tk1[i1] = t; tw1[i1] = w;                          // v[i1]*w
    }
}

// ---------------- pass 1: per-chunk per-label counts ----------------------
__global__ void __launch_bounds__(128) count_kernel(const int* __restrict__ mask1,
                                                    const int* __restrict__ mask2,
                                                    unsigned* __restrict__ counts,
                                                    int B, int ppc) {
    __shared__ unsigned cnt[2][NI];
    int wave = threadIdx.x >> 6, lane = threadIdx.x & 63;
    unsigned* c = cnt[wave];
    for (int j = lane; j < NI; j += 64) c[j] = 0u;
    __syncthreads();
    int chunk = blockIdx.x * 2 + wave;          // 0..2B-1 ; chunk = img*B + b
    int img = chunk / B, b = chunk % B;
    const int* mask = img ? mask2 : mask1;
    long base = (long)b * ppc;
    for (int t = 0; t < ppc; t += 64) {
        int l = mask[base + t + lane] - 1;
        atomicAdd(&c[l], 1u);
    }
    __syncthreads();
    unsigned* dst = counts + (long)chunk * NI;  // layout [img][b][l], l contiguous
    for (int j = lane; j < NI; j += 64) dst[j] = c[j];
}

// ---------------- pass 2: exclusive scan over chunks, per label -----------
__global__ void scan_kernel(unsigned* __restrict__ counts, unsigned* __restrict__ totals, int B) {
    int t = blockIdx.x * blockDim.x + threadIdx.x;   // 0..2*NI-1 = (img,l)
    if (t >= 2*NI) return;
    int img = t / NI, l = t % NI;
    unsigned run = 0;
    unsigned* p = counts + (long)img * B * NI + l;
    for (int b = 0; b < B; ++b) {
        unsigned c = p[(long)b * NI];
        p[(long)b * NI] = run;
        run += c;
    }
    totals[t] = run;
}

// ---------------- pass 3: rank + scatter contributions --------------------
__global__ void __launch_bounds__(128) scatter_kernel(
        const float* __restrict__ img1, const float* __restrict__ img2,
        const float* __restrict__ flow1, const float* __restrict__ flow2,
        const int* __restrict__ mask1, const int* __restrict__ mask2,
        const unsigned* __restrict__ counts,
        const int* __restrict__ tk0, const float* __restrict__ tw0,
        const int* __restrict__ tk1, const float* __restrict__ tw1,
        float* __restrict__ out, float* __restrict__ zf, int B, int ppc) {
    __shared__ int   run[2][NI];                  // per-wave running per-label cursor
    __shared__ int   s_k0[MAXPIX]; __shared__ float s_w0[MAXPIX];
    __shared__ int   s_k1[MAXPIX]; __shared__ float s_w1[MAXPIX];
    int wave = threadIdx.x >> 6, lane = threadIdx.x & 63;
    for (int j = threadIdx.x; j < MAXPIX; j += 128) {
        s_k0[j] = tk0[j]; s_w0[j] = tw0[j]; s_k1[j] = tk1[j]; s_w1[j] = tw1[j];
    }
    int chunk = blockIdx.x * 2 + wave;
    int img = chunk / B, b = chunk % B;
    const unsigned* cbase = counts + (long)chunk * NI;
    int* r = run[wave];
    for (int j = lane; j < NI; j += 64) r[j] = (int)cbase[j];
    __syncthreads();
    const int*   mask  = img ? mask2  : mask1;
    const float* image = img ? img2   : img1;
    const float* flow  = img ? flow2  : flow1;
    float* zfi = zf + img * NI;
    long base = (long)b * ppc;
    for (int t = 0; t < ppc; t += 64) {
        long p = base + t + lane;
        int l = mask[p] - 1;
        float iv = image[p];
        float fx = flow[p], fy = flow[HW + p], fz = flow[2L*HW + p];
        // lanes with equal label (12-bit) via ballot match
        unsigned long long m = ~0ull;
        #pragma unroll
        for (int bit = 0; bit < 12; ++bit) {
            unsigned long long bb = __ballot((l >> bit) & 1);
            m &= ((l >> bit) & 1) ? bb : ~bb;
        }
        int cb = __popcll(m & ((1ull << lane) - 1ull));   // same-label lanes before me
        int ct = __popcll(m);                             // same-label lanes total
        int r0 = r[l];
        int rank = r0 + cb;                               // stable raster rank within label
        if (cb == ct - 1) r[l] = r0 + ct;                 // last lane advances cursor
        int row = img * NI + l;
        float* xrow = out + (long)row * FEAT;
        int k0 = s_k0[rank];
        if (k0 >= 0) atomicAdd(&xrow[k0], s_w0[rank] * iv);
        int k1 = s_k1[rank];
        if (k1 >= 0) atomicAdd(&xrow[k1], s_w1[rank] * iv);
        int cx = fx < 0.f ? 0 : (fx == 0.f ? 1 : 2);
        int cy = fy < 0.f ? 0 : (fy == 0.f ? 1 : 2);
        atomicAdd(&xrow[200 + cx*3 + cy], 1.0f);
        atomicAdd(&zfi[l], fz);
    }
}

// ---------------- edges: top-2 nearest centers ----------------------------
__device__ __forceinline__ bool better(float d, int j, float d2, int j2) {
    return d < d2 || (d == d2 && j < j2);   // stable-argsort tie-break
}

__global__ void __launch_bounds__(256) edge_kernel(const float* __restrict__ bbox1,
                                                   const float* __restrict__ bbox2,
                                                   const float* __restrict__ zf,
                                                   const unsigned* __restrict__ totals,
                                                   float* __restrict__ out) {
    int wave = threadIdx.x >> 6, lane = threadIdx.x & 63;
    int i = blockIdx.x * 4 + wave;                 // row; grid = NI/4
    float c1x = bbox1[i*4 + 0], c1y = bbox1[i*4 + 1];
    float d0 = INFINITY; int j0 = 0x7fffffff;
    float d1 = INFINITY; int j1 = 0x7fffffff;
    for (int t = 0; t < NI; t += 64) {
        int j = t + lane;
        float dx = c1x - bbox2[j*4 + 0];
        float dy = c1y - bbox2[j*4 + 1];
        float dsq = dx*dx + dy*dy;                 // contract off: no fma, matches np
        float d = (float)sqrt((double)dsq);        // correctly-rounded f32 sqrt (np-exact)
        if (better(d, j, d0, j0)) { d1 = d0; j1 = j0; d0 = d; j0 = j; }
        else if (better(d, j, d1, j1)) { d1 = d; j1 = j; }
    }
    for (int off = 32; off; off >>= 1) {
        float od0 = __shfl_down(d0, off); int oj0 = __shfl_down(j0, off);
        float od1 = __shfl_down(d1, off); int oj1 = __shfl_down(j1, off);
        if (better(od0, oj0, d0, j0)) {
            if (better(d0, j0, od1, oj1)) { d1 = d0; j1 = j0; }
            else                          { d1 = od1; j1 = oj1; }
            d0 = od0; j0 = oj0;
        } else if (better(od0, oj0, d1, j1)) { d1 = od0; j1 = oj0; }
    }
    if (lane == 0) {
        float z1 = zf[i] / (float)totals[i];
        int js[2] = { j0, j1 };
        for (int t = 0; t < 2; ++t) {
            int e = i*2 + t, j = js[t];
            out[EIOFF + e]      = (float)i;
            out[EIOFF + NE + e] = (float)(j + NI);
            float* ea = out + EAOFF + (long)e * 6;
            ea[0] = z1;
            ea[1] = zf[NI + j] / (float)totals[NI + j];
            ea[2] = c1x - bbox2[j*4 + 0];
            ea[3] = c1y - bbox2[j*4 + 1];
            ea[4] = bbox1[i*4 + 2] / bbox2[j*4 + 2];
            ea[5] = bbox1[i*4 + 3] / bbox2[j*4 + 3];
        }
    }
}

extern "C" void kernel_launch(void* const* d_in, const int* in_sizes, int n_in,
                              void* d_out, int out_size, void* d_ws, size_t ws_size,
                              hipStream_t stream) {
    const float* img1  = (const float*)d_in[0];
    const float* img2  = (const float*)d_in[1];
    const float* flow1 = (const float*)d_in[2];
    const float* flow2 = (const float*)d_in[3];
    const float* bbox1 = (const float*)d_in[4];
    const float* bbox2 = (const float*)d_in[5];
    const int*   mask1 = (const int*)d_in[6];
    const int*   mask2 = (const int*)d_in[7];
    float* out = (float*)d_out;

    // pick chunk count B (per image) to fit workspace
    int B = 1024;
    while (B > 64) {
        size_t need = (size_t)2 * B * NI * 4 + (size_t)2 * (2*NI*4) + (size_t)MAXPIX * 16;
        if (need <= ws_size) break;
        B >>= 1;
    }
    int ppc = HW / B;   // pixels per chunk (multiple of 64)

    char* ws = (char*)d_ws;
    unsigned* counts = (unsigned*)ws;
    size_t off = (size_t)2 * B * NI * 4;
    float*    zf     = (float*)(ws + off); off += 2*NI*4;
    unsigned* totals = (unsigned*)(ws + off); off += 2*NI*4;
    int*   tk0 = (int*)(ws + off);   off += MAXPIX*4;
    float* tw0 = (float*)(ws + off); off += MAXPIX*4;
    int*   tk1 = (int*)(ws + off);   off += MAXPIX*4;
    float* tw1 = (float*)(ws + off); off += MAXPIX*4;

    hipLaunchKernelGGL(zero_kernel, dim3((XSIZE + 255) / 256), dim3(256), 0, stream, out, zf);
    hipLaunchKernelGGL(table_kernel, dim3(1), dim3(256), 0, stream, tk0, tw0, tk1, tw1);
    hipLaunchKernelGGL(count_kernel, dim3(B), dim3(128), 0, stream, mask1, mask2, counts, B, ppc);
    hipLaunchKernelGGL(scan_kernel, dim3((2*NI + 255) / 256), dim3(256), 0, stream, counts, totals, B);
    hipLaunchKernelGGL(scatter_kernel, dim3(B), dim3(128), 0, stream,
                       img1, img2, flow1, flow2, mask1, mask2, counts,
                       tk0, tw0, tk1, tw1, out, zf, B, ppc);
    hipLaunchKernelGGL(edge_kernel, dim3(NI / 4), dim3(256), 0, stream, bbox1, bbox2, zf, totals, out);
}

// Round 2
// 782.789 us; speedup vs baseline: 2.1698x; 2.1698x over previous
//
#include <hip/hip_runtime.h>
#include <math.h>

#pragma clang fp contract(off)

#define HW      (2048*2048)
#define NI      4096        // instances per image
#define MAXPIX  1024        // pixels per instance (equal partition)
#define NF      200
#define FEAT    209
#define NE      (NI*2)      // edges = N1 * TOPN
#define XSIZE   ((2*NI)*FEAT)
#define EIOFF   XSIZE
#define EAOFF   (EIOFF + 2*NE)

// ---------------- pass 1: per-chunk per-label counts ----------------------
__global__ void __launch_bounds__(128) count_kernel(const int* __restrict__ mask1,
                                                    const int* __restrict__ mask2,
                                                    unsigned* __restrict__ counts,
                                                    int B, int ppc) {
    __shared__ unsigned cnt[2][NI];
    int wave = threadIdx.x >> 6, lane = threadIdx.x & 63;
    unsigned* c = cnt[wave];
    for (int j = lane; j < NI; j += 64) c[j] = 0u;
    __syncthreads();
    int chunk = blockIdx.x * 2 + wave;          // chunk = img*B + b
    int img = chunk / B, b = chunk % B;
    const int* mask = img ? mask2 : mask1;
    long base = (long)b * ppc;
    for (int t = 0; t < ppc; t += 64) {
        int l = mask[base + t + lane] - 1;
        atomicAdd(&c[l], 1u);
    }
    __syncthreads();
    unsigned* dst = counts + (long)chunk * NI;  // layout [img][b][l]
    for (int j = lane; j < NI; j += 64) dst[j] = c[j];
}

// ---------------- pass 2: exclusive scan over chunks, per label -----------
__global__ void scan_kernel(unsigned* __restrict__ counts, unsigned* __restrict__ totals, int B) {
    int t = blockIdx.x * blockDim.x + threadIdx.x;   // (img,l)
    if (t >= 2*NI) return;
    int img = t / NI, l = t % NI;
    unsigned run = 0;
    unsigned* p = counts + (long)img * B * NI + l;
    for (int b = 0; b < B; ++b) {
        unsigned c = p[(long)b * NI];
        p[(long)b * NI] = run;
        run += c;
    }
    totals[t] = run;
}

// ---------------- pass 3: rank + scatter values (NO atomics) --------------
__global__ void __launch_bounds__(128) scatter_kernel(
        const float* __restrict__ img1, const float* __restrict__ img2,
        const float* __restrict__ flow1, const float* __restrict__ flow2,
        const int* __restrict__ mask1, const int* __restrict__ mask2,
        const unsigned* __restrict__ counts,
        float2* __restrict__ svz, unsigned char* __restrict__ sbin,
        unsigned* __restrict__ sidx,
        int B, int ppc, int mode) {
    __shared__ int run[2][NI];                  // per-wave per-label cursor
    int wave = threadIdx.x >> 6, lane = threadIdx.x & 63;
    int chunk = blockIdx.x * 2 + wave;
    int img = chunk / B, b = chunk % B;
    const unsigned* cbase = counts + (long)chunk * NI;
    int* r = run[wave];
    for (int j = lane; j < NI; j += 64) r[j] = (int)cbase[j];
    __syncthreads();
    const int*   mask  = img ? mask2  : mask1;
    const float* image = img ? img2   : img1;
    const float* flow  = img ? flow2  : flow1;
    long base = (long)b * ppc;
    for (int t = 0; t < ppc; t += 64) {
        long p = base + t + lane;
        int l = mask[p] - 1;
        // lanes with equal label (12-bit) via ballot match
        unsigned long long m = ~0ull;
        #pragma unroll
        for (int bit = 0; bit < 12; ++bit) {
            unsigned long long bb = __ballot((l >> bit) & 1);
            m &= ((l >> bit) & 1) ? bb : ~bb;
        }
        int cb = __popcll(m & ((1ull << lane) - 1ull));
        int ct = __popcll(m);
        int r0 = r[l];
        int rank = r0 + cb;                        // stable raster rank in label
        if (cb == ct - 1) r[l] = r0 + ct;
        long dst = (long)(img * NI + l) * MAXPIX + rank;
        if (mode == 0) {
            float iv = image[p];
            float fx = flow[p], fy = flow[HW + p], fz = flow[2L*HW + p];
            int cx = fx < 0.f ? 0 : (fx == 0.f ? 1 : 2);
            int cy = fy < 0.f ? 0 : (fy == 0.f ? 1 : 2);
            svz[dst] = make_float2(iv, fz);
            sbin[dst] = (unsigned char)(cx * 3 + cy);
        } else {
            sidx[dst] = (unsigned)p;               // within-image pixel index
        }
    }
}

// ---------------- pass 4: per-instance features (coalesced) ---------------
__global__ void __launch_bounds__(256) feat_kernel(
        const float2* __restrict__ svz, const unsigned char* __restrict__ sbin,
        const unsigned* __restrict__ sidx,
        const float* __restrict__ img1, const float* __restrict__ img2,
        const float* __restrict__ flow1, const float* __restrict__ flow2,
        const unsigned* __restrict__ totals,
        float* __restrict__ out, float* __restrict__ zfm, int mode) {
    __shared__ float iv[MAXPIX];
    __shared__ float wsum[4];
    __shared__ int hist[9];
    int row = blockIdx.x;            // 0..2*NI-1
    int t = threadIdx.x;
    int cnt = (int)totals[row];
    if (t < 9) hist[t] = 0;
    __syncthreads();
    float fzsum = 0.f;
    long base = (long)row * MAXPIX;
    int j0 = t * 4;
    if (mode == 0) {
        // two float4 loads = 2 packed {iv,fz} entries each
        float4 a = ((const float4*)(svz + base))[t*2 + 0];
        float4 c = ((const float4*)(svz + base))[t*2 + 1];
        iv[j0+0] = a.x; iv[j0+1] = a.z; iv[j0+2] = c.x; iv[j0+3] = c.z;
        float zs[4] = { a.y, a.w, c.y, c.w };
        uchar4 b4 = ((const uchar4*)(sbin + base))[t];
        unsigned char bs[4] = { b4.x, b4.y, b4.z, b4.w };
        #pragma unroll
        for (int u = 0; u < 4; ++u)
            if (j0 + u < cnt) { fzsum += zs[u]; atomicAdd(&hist[bs[u]], 1); }
    } else {
        const float* image = row < NI ? img1 : img2;
        const float* flow  = row < NI ? flow1 : flow2;
        uint4 i4 = ((const uint4*)(sidx + base))[t];
        unsigned ids[4] = { i4.x, i4.y, i4.z, i4.w };
        #pragma unroll
        for (int u = 0; u < 4; ++u) {
            int j = j0 + u;
            if (j < cnt) {
                long p = (long)ids[u];
                float v = image[p];
                iv[j] = v;
                float fx = flow[p], fy = flow[HW + p], fz = flow[2L*HW + p];
                fzsum += fz;
                int cx = fx < 0.f ? 0 : (fx == 0.f ? 1 : 2);
                int cy = fy < 0.f ? 0 : (fy == 0.f ? 1 : 2);
                atomicAdd(&hist[cx * 3 + cy], 1);
            } else iv[j] = 0.f;
        }
    }
    // block-reduce fz
    for (int off = 32; off; off >>= 1) fzsum += __shfl_down(fzsum, off);
    if ((t & 63) == 0) wsum[t >> 6] = fzsum;
    __syncthreads();
    if (t == 0) zfm[row] = (wsum[0] + wsum[1] + wsum[2] + wsum[3]) / (float)cnt;
    if (t < NF) {
        float Lf = (float)cnt;
        float p = ((float)t + 0.5f) * (Lf / (float)NF) - 0.5f;
        p = fminf(fmaxf(p, 0.0f), Lf - 1.0f);
        int i0 = (int)floorf(p);
        int i1 = min(i0 + 1, cnt - 1);
        float w = p - (float)i0;
        out[(long)row * FEAT + t] = iv[i0] * (1.0f - w) + iv[i1] * w;   // contract off
    } else if (t < FEAT) {
        out[(long)row * FEAT + t] = (float)hist[t - NF];
    }
}

// ---------------- edges: top-2 nearest centers ----------------------------
__device__ __forceinline__ bool better(float d, int j, float d2, int j2) {
    return d < d2 || (d == d2 && j < j2);   // stable-argsort tie-break
}

__global__ void __launch_bounds__(256) edge_kernel(const float* __restrict__ bbox1,
                                                   const float* __restrict__ bbox2,
                                                   const float* __restrict__ zfm,
                                                   float* __restrict__ out) {
    int wave = threadIdx.x >> 6, lane = threadIdx.x & 63;
    int i = blockIdx.x * 4 + wave;
    float c1x = bbox1[i*4 + 0], c1y = bbox1[i*4 + 1];
    float d0 = INFINITY; int j0 = 0x7fffffff;
    float d1 = INFINITY; int j1 = 0x7fffffff;
    for (int t = 0; t < NI; t += 64) {
        int j = t + lane;
        float dx = c1x - bbox2[j*4 + 0];
        float dy = c1y - bbox2[j*4 + 1];
        float dsq = dx*dx + dy*dy;                 // no fma (contract off)
        float d = (float)sqrt((double)dsq);        // correctly-rounded f32 sqrt
        if (better(d, j, d0, j0)) { d1 = d0; j1 = j0; d0 = d; j0 = j; }
        else if (better(d, j, d1, j1)) { d1 = d; j1 = j; }
    }
    for (int off = 32; off; off >>= 1) {
        float od0 = __shfl_down(d0, off); int oj0 = __shfl_down(j0, off);
        float od1 = __shfl_down(d1, off); int oj1 = __shfl_down(j1, off);
        if (better(od0, oj0, d0, j0)) {
            if (better(d0, j0, od1, oj1)) { d1 = d0; j1 = j0; }
            else                          { d1 = od1; j1 = oj1; }
            d0 = od0; j0 = oj0;
        } else if (better(od0, oj0, d1, j1)) { d1 = od0; j1 = oj0; }
    }
    if (lane == 0) {
        float z1 = zfm[i];
        int js[2] = { j0, j1 };
        for (int t = 0; t < 2; ++t) {
            int e = i*2 + t, j = js[t];
            out[EIOFF + e]      = (float)i;
            out[EIOFF + NE + e] = (float)(j + NI);
            float* ea = out + EAOFF + (long)e * 6;
            ea[0] = z1;
            ea[1] = zfm[NI + j];
            ea[2] = c1x - bbox2[j*4 + 0];
            ea[3] = c1y - bbox2[j*4 + 1];
            ea[4] = bbox1[i*4 + 2] / bbox2[j*4 + 2];
            ea[5] = bbox1[i*4 + 3] / bbox2[j*4 + 3];
        }
    }
}

extern "C" void kernel_launch(void* const* d_in, const int* in_sizes, int n_in,
                              void* d_out, int out_size, void* d_ws, size_t ws_size,
                              hipStream_t stream) {
    const float* img1  = (const float*)d_in[0];
    const float* img2  = (const float*)d_in[1];
    const float* flow1 = (const float*)d_in[2];
    const float* flow2 = (const float*)d_in[3];
    const float* bbox1 = (const float*)d_in[4];
    const float* bbox2 = (const float*)d_in[5];
    const int*   mask1 = (const int*)d_in[6];
    const int*   mask2 = (const int*)d_in[7];
    float* out = (float*)d_out;

    const size_t SVZ_BYTES  = (size_t)2 * NI * MAXPIX * 8;   // 67.1 MB
    const size_t SBIN_BYTES = (size_t)2 * NI * MAXPIX;       //  8.4 MB
    const size_t SIDX_BYTES = (size_t)2 * NI * MAXPIX * 4;   // 33.5 MB
    const size_t SMALL      = (size_t)2 * NI * 4 * 2;        // zfm + totals

    int mode = 0, B = 1024;
    while (B > 64 && (size_t)2*B*NI*4 + SVZ_BYTES + SBIN_BYTES + SMALL > ws_size) B >>= 1;
    if ((size_t)2*B*NI*4 + SVZ_BYTES + SBIN_BYTES + SMALL > ws_size) {
        mode = 1; B = 1024;
        while (B > 16 && (size_t)2*B*NI*4 + SIDX_BYTES + SMALL > ws_size) B >>= 1;
    }
    int ppc = HW / B;

    char* ws = (char*)d_ws;
    unsigned* counts = (unsigned*)ws;
    size_t off = (size_t)2 * B * NI * 4;
    float2*        svz  = nullptr;
    unsigned char* sbin = nullptr;
    unsigned*      sidx = nullptr;
    if (mode == 0) {
        svz  = (float2*)(ws + off);        off += SVZ_BYTES;
        sbin = (unsigned char*)(ws + off); off += SBIN_BYTES;
    } else {
        sidx = (unsigned*)(ws + off);      off += SIDX_BYTES;
    }
    unsigned* totals = (unsigned*)(ws + off); off += 2*NI*4;
    float*    zfm    = (float*)(ws + off);    off += 2*NI*4;

    hipLaunchKernelGGL(count_kernel, dim3(B), dim3(128), 0, stream, mask1, mask2, counts, B, ppc);
    hipLaunchKernelGGL(scan_kernel, dim3((2*NI + 255) / 256), dim3(256), 0, stream, counts, totals, B);
    hipLaunchKernelGGL(scatter_kernel, dim3(B), dim3(128), 0, stream,
                       img1, img2, flow1, flow2, mask1, mask2, counts,
                       svz, sbin, sidx, B, ppc, mode);
    hipLaunchKernelGGL(feat_kernel, dim3(2*NI), dim3(256), 0, stream,
                       svz, sbin, sidx, img1, img2, flow1, flow2, totals, out, zfm, mode);
    hipLaunchKernelGGL(edge_kernel, dim3(NI / 4), dim3(256), 0, stream, bbox1, bbox2, zfm, out);
}